// Round 3
// baseline (503.716 us; speedup 1.0000x reference)
//
#include <hip/hip_runtime.h>
#include <math.h>

#define BB 4
#define TT 200
#define UU 101
#define VV 1024
#define NCELL (BB*TT*UU)   // 80800
#define PAD 102            // LDS row pitch

__device__ __forceinline__ float f4max(const float4& v) {
    return fmaxf(fmaxf(v.x, v.y), fmaxf(v.z, v.w));
}
__device__ __forceinline__ float f4comp(const float4& v, int c) {
    switch (c & 3) { case 0: return v.x; case 1: return v.y; case 2: return v.z; default: return v.w; }
}

// Kernel 1: one 64-lane wave per (b,t,u) cell. LSE over V=1024.
// Cells with u > lab never reach the loss -> skip their 4KB read entirely.
// Block 0 also zeroes the completion counter used by alpha's fused finalize.
__global__ __launch_bounds__(256) void lse_kernel(
        const float* __restrict__ logits,
        const int*   __restrict__ labels,     // [B, U-1]
        const int*   __restrict__ lab_lens,   // [B]
        float* __restrict__ blank_lp,         // [B, T, U]
        float* __restrict__ label_lp,         // [B, T, U-1]
        int*   __restrict__ done_ctr) {       // [1]
    if (blockIdx.x == 0 && threadIdx.x == 0) *done_ctr = 0;  // ordered by kernel boundary

    const int wave = threadIdx.x >> 6;
    const int lane = threadIdx.x & 63;
    const int cell = blockIdx.x * 4 + wave;
    if (cell >= NCELL) return;
    const int b   = cell / (TT * UU);
    const int rem = cell % (TT * UU);
    const int t   = rem / UU;
    const int u   = rem % UU;

    int lab = lab_lens[b];
    lab = min(max(lab, 0), UU - 1);
    if (u > lab) return;                      // dead cell

    const float4* src = (const float4*)(logits + (size_t)cell * VV);
    float4 x0 = src[lane];
    float4 x1 = src[lane + 64];
    float4 x2 = src[lane + 128];
    float4 x3 = src[lane + 192];

    float m = fmaxf(fmaxf(f4max(x0), f4max(x1)), fmaxf(f4max(x2), f4max(x3)));
    #pragma unroll
    for (int off = 32; off; off >>= 1) m = fmaxf(m, __shfl_xor(m, off));

    float s = 0.f;
    s += __expf(x0.x - m) + __expf(x0.y - m) + __expf(x0.z - m) + __expf(x0.w - m);
    s += __expf(x1.x - m) + __expf(x1.y - m) + __expf(x1.z - m) + __expf(x1.w - m);
    s += __expf(x2.x - m) + __expf(x2.y - m) + __expf(x2.z - m) + __expf(x2.w - m);
    s += __expf(x3.x - m) + __expf(x3.y - m) + __expf(x3.z - m) + __expf(x3.w - m);
    #pragma unroll
    for (int off = 32; off; off >>= 1) s += __shfl_xor(s, off);

    const float lse = m + __logf(s);

    if (lane == 0) blank_lp[cell] = x0.x - lse;   // vocab 0 lives in lane 0, x0.x

    if (u < lab) {
        int l = labels[b * (UU - 1) + u];
        l = min(max(l, 0), VV - 1);
        const int lane_l = (l >> 2) & 63;
        if (lane == lane_l) {
            const int j = l >> 8;
            const int c = l & 3;
            float val = (j == 0) ? f4comp(x0, c) : (j == 1) ? f4comp(x1, c)
                      : (j == 2) ? f4comp(x2, c) : f4comp(x3, c);
            label_lp[(b * TT + t) * (UU - 1) + u] = val - lse;
        }
    }
}

// Kernel 2: one block per batch. Stage blank/label (u <= lab only) into LDS,
// then wave 0 runs the anti-diagonal recursion out of LDS + registers.
// Interleaved columns: lane l owns u=2l (A) and u=2l+1 (B). The odd column's
// left-dep is in-register (leftB = aA); only ONE shfl_up per diagonal.
// Last block to finish computes the mean (fused finalize via atomic ticket).
__global__ __launch_bounds__(256) void alpha_kernel(
        const float* __restrict__ blank_lp,
        const float* __restrict__ label_lp,
        const int*   __restrict__ lab_lens,   // [B]
        const int*   __restrict__ attn,       // [B, T]
        float* __restrict__ loss_b,           // [B]
        int*   __restrict__ valid_b,          // [B]
        int*   __restrict__ done_ctr,         // [1]
        float* __restrict__ out) {            // [1]
    const int b    = blockIdx.x;
    const int tid  = threadIdx.x;
    const int lane = tid & 63;
    const int wave = tid >> 6;

    extern __shared__ float smem[];
    float* bs = smem;              // [TT][PAD] blank
    float* ls = smem + TT * PAD;   // [TT][PAD] label

    int lab = lab_lens[b];
    lab = min(max(lab, 0), UU - 1);

    const float* bl = blank_lp + b * TT * UU;
    const float* lb = label_lp + b * TT * (UU - 1);

    // ---- stage rows (only columns that exist: u <= lab / u < lab) ----
    for (int t = wave; t < TT; t += 4) {
        const float* brow = bl + t * UU;
        float*       bsr  = bs + t * PAD;
        for (int u = lane; u <= lab; u += 64) bsr[u] = brow[u];
        const float* lrow = lb + t * (UU - 1);
        float*       lsr  = ls + t * PAD;
        for (int u = lane; u < lab; u += 64) lsr[u] = lrow[u];
    }
    __syncthreads();
    if (tid >= 64) return;          // recursion is wave 0 only; no barriers after

    // input length = clip(sum(attn[b,:]), 1, T)
    int acc = 0;
    for (int i = lane; i < TT; i += 64) acc += attn[b * TT + i];
    #pragma unroll
    for (int off = 32; off; off >>= 1) acc += __shfl_xor(acc, off);
    const int tmax = min(max(acc, 1), TT) - 1;
    const int ndiag = tmax + lab + 1;

    const int uA = lane * 2;                 // even column
    const int uB = uA + 1;                   // odd column
    const int cA = min(uA, UU - 1);          // clamped LDS cols
    const int cB = min(uB, UU - 1);
    const int eA = min(max(uA - 1, 0), UU - 2);
    const int eB = min(uB - 1, UU - 2);      // = cA when in range

    auto fetch = [&](int d, float& fbA, float& flA, float& fbB, float& flB) {
        int tA = min(max(d - uA, 0), TT - 1);
        int tB = min(max(d - uB, 0), TT - 1);
        fbA = bs[tA * PAD + cA];
        flA = ls[tA * PAD + eA];
        fbB = bs[tB * PAD + cB];
        flB = ls[tB * PAD + eB];
    };

    float aA = -INFINITY, aB = -INFINITY;

    float cbA[4], clA[4], cbB[4], clB[4];
    float nbA[4], nlA[4], nbB[4], nlB[4];
    #pragma unroll
    for (int k = 0; k < 4; ++k) fetch(k, cbA[k], clA[k], cbB[k], clB[k]);

    const int ng = (ndiag + 3) >> 2;
    for (int g = 0; g < ng; ++g) {
        const int dbase = g * 4;
        #pragma unroll
        for (int k = 0; k < 4; ++k) fetch(dbase + 4 + k, nbA[k], nlA[k], nbB[k], nlB[k]);
        #pragma unroll
        for (int k = 0; k < 4; ++k) {
            const int d = dbase + k;
            if (d < ndiag) {                       // wave-uniform
                const float leftA = __shfl_up(aB, 1);   // alpha[d-1][uA-1] (lane l-1's B)
                const float leftB = aA;                 // alpha[d-1][uB-1] in-register!
                const int tA = d - uA;
                const int tB = d - uB;
                // slot A (even col)
                {
                    const float x  = aA + cbA[k];
                    const float y  = leftA + clA[k];
                    const float mx = fmaxf(x, y), mn = fminf(x, y);
                    const float full = mx + __logf(1.f + __expf(mn - mx));
                    const float v = (d == 0) ? cbA[k]
                                  : (uA == 0) ? x
                                  : (tA == 0) ? y
                                  : full;
                    const bool act = (uA <= lab) && (tA >= 0) && (tA <= tmax);
                    aA = act ? v : aA;
                }
                // slot B (odd col, uB >= 1; never active at d==0)
                {
                    const float x  = aB + cbB[k];
                    const float y  = leftB + clB[k];
                    const float mx = fmaxf(x, y), mn = fminf(x, y);
                    const float full = mx + __logf(1.f + __expf(mn - mx));
                    const float v = (tB == 0) ? y : full;
                    const bool act = (uB <= lab) && (tB >= 0) && (tB <= tmax);
                    aB = act ? v : aB;
                }
            }
        }
        #pragma unroll
        for (int k = 0; k < 4; ++k) { cbA[k] = nbA[k]; clA[k] = nlA[k];
                                      cbB[k] = nbB[k]; clB[k] = nlB[k]; }
    }

    // loss = -alpha[tmax, lab]; col lab -> lane lab>>1, slot (lab&1)
    const float cand = (lab & 1) ? aB : aA;
    const float v = __shfl(cand, lab >> 1);

    if (lane == 0) {
        atomicExch(&loss_b[b], -v);
        atomicExch(&valid_b[b], (lab > 0) ? 1 : 0);
        __threadfence();
        const int prev = atomicAdd(done_ctr, 1);
        if (prev == BB - 1) {                  // last block finalizes
            float s = 0.f; int nv = 0;
            #pragma unroll
            for (int i = 0; i < BB; ++i) {
                const float li = atomicAdd(&loss_b[i], 0.0f);   // device-scope read
                const int   vi = atomicAdd(&valid_b[i], 0);
                if (vi) { s += li; ++nv; }
            }
            out[0] = s / (float)max(nv, 1);
        }
    }
}

extern "C" void kernel_launch(void* const* d_in, const int* in_sizes, int n_in,
                              void* d_out, int out_size, void* d_ws, size_t ws_size,
                              hipStream_t stream) {
    const float* logits   = (const float*)d_in[0];
    const int*   labels   = (const int*)d_in[1];
    const int*   lab_lens = (const int*)d_in[2];
    const int*   attn     = (const int*)d_in[3];

    float* ws      = (float*)d_ws;
    float* blank   = ws;                           // B*T*U
    float* label   = blank + BB * TT * UU;         // B*T*(U-1)
    float* loss_b  = label + BB * TT * (UU - 1);   // B
    int*   valid_b = (int*)(loss_b + BB);          // B
    int*   done    = valid_b + BB;                 // 1

    static bool attr_set = false;
    if (!attr_set) {
        hipFuncSetAttribute((const void*)alpha_kernel,
                            hipFuncAttributeMaxDynamicSharedMemorySize,
                            2 * TT * PAD * (int)sizeof(float));   // 163,200 B <= 160 KiB
        attr_set = true;
    }

    lse_kernel<<<(NCELL + 3) / 4, 256, 0, stream>>>(logits, labels, lab_lens,
                                                    blank, label, done);
    alpha_kernel<<<BB, 256, 2 * TT * PAD * sizeof(float), stream>>>(
        blank, label, lab_lens, attn, loss_b, valid_b, done, (float*)d_out);
}

// Round 4
// 464.985 us; speedup vs baseline: 1.0833x; 1.0833x over previous
//
#include <hip/hip_runtime.h>
#include <math.h>

#define BB 4
#define TT 200
#define UU 101
#define VV 1024
#define NCELL (BB*TT*UU)   // 80800
#define PAD 102            // LDS row pitch

__device__ __forceinline__ float f4max(const float4& v) {
    return fmaxf(fmaxf(v.x, v.y), fmaxf(v.z, v.w));
}
__device__ __forceinline__ float f4comp(const float4& v, int c) {
    switch (c & 3) { case 0: return v.x; case 1: return v.y; case 2: return v.z; default: return v.w; }
}

// Kernel 1: one 64-lane wave per (b,t,u) cell. LSE over V=1024.
// Cells with u > lab never reach the loss -> skip their 4KB read entirely.
__global__ __launch_bounds__(256) void lse_kernel(
        const float* __restrict__ logits,
        const int*   __restrict__ labels,     // [B, U-1]
        const int*   __restrict__ lab_lens,   // [B]
        float* __restrict__ blank_lp,         // [B, T, U]
        float* __restrict__ label_lp) {       // [B, T, U-1]
    const int wave = threadIdx.x >> 6;
    const int lane = threadIdx.x & 63;
    const int cell = blockIdx.x * 4 + wave;
    if (cell >= NCELL) return;
    const int b   = cell / (TT * UU);
    const int rem = cell % (TT * UU);
    const int t   = rem / UU;
    const int u   = rem % UU;

    int lab = lab_lens[b];
    lab = min(max(lab, 0), UU - 1);
    if (u > lab) return;                      // dead cell

    const float4* src = (const float4*)(logits + (size_t)cell * VV);
    float4 x0 = src[lane];
    float4 x1 = src[lane + 64];
    float4 x2 = src[lane + 128];
    float4 x3 = src[lane + 192];

    float m = fmaxf(fmaxf(f4max(x0), f4max(x1)), fmaxf(f4max(x2), f4max(x3)));
    #pragma unroll
    for (int off = 32; off; off >>= 1) m = fmaxf(m, __shfl_xor(m, off));

    float s = 0.f;
    s += __expf(x0.x - m) + __expf(x0.y - m) + __expf(x0.z - m) + __expf(x0.w - m);
    s += __expf(x1.x - m) + __expf(x1.y - m) + __expf(x1.z - m) + __expf(x1.w - m);
    s += __expf(x2.x - m) + __expf(x2.y - m) + __expf(x2.z - m) + __expf(x2.w - m);
    s += __expf(x3.x - m) + __expf(x3.y - m) + __expf(x3.z - m) + __expf(x3.w - m);
    #pragma unroll
    for (int off = 32; off; off >>= 1) s += __shfl_xor(s, off);

    const float lse = m + __logf(s);

    if (lane == 0) blank_lp[cell] = x0.x - lse;   // vocab 0 lives in lane 0, x0.x

    if (u < lab) {
        int l = labels[b * (UU - 1) + u];
        l = min(max(l, 0), VV - 1);
        const int lane_l = (l >> 2) & 63;
        if (lane == lane_l) {
            const int j = l >> 8;
            const int c = l & 3;
            float val = (j == 0) ? f4comp(x0, c) : (j == 1) ? f4comp(x1, c)
                      : (j == 2) ? f4comp(x2, c) : f4comp(x3, c);
            label_lp[(b * TT + t) * (UU - 1) + u] = val - lse;
        }
    }
}

// Kernel 2: one block per batch. Stage blank+label into LDS with the proven
// fully-coalesced fixed-trip loop (r2), then wave 0 runs the anti-diagonal
// recursion out of LDS + registers with INTERLEAVED columns: lane l owns
// u=2l (A) and u=2l+1 (B), so the odd column's left-dep is in-register
// (leftB = aA) and only ONE shfl_up sits on the serial chain per diagonal.
__global__ __launch_bounds__(256) void alpha_kernel(
        const float* __restrict__ blank_lp,
        const float* __restrict__ label_lp,
        const int*   __restrict__ lab_lens,   // [B]
        const int*   __restrict__ attn,       // [B, T]
        float* __restrict__ loss_b,           // [B]
        int*   __restrict__ valid_b) {        // [B]
    const int b    = blockIdx.x;
    const int tid  = threadIdx.x;
    const int lane = tid & 63;

    extern __shared__ float smem[];
    float* bs = smem;              // [TT][PAD] blank
    float* ls = smem + TT * PAD;   // [TT][PAD] label

    const float* bl = blank_lp + b * TT * UU;
    const float* lb = label_lp + b * TT * (UU - 1);

    // ---- stage blank/label into LDS (coalesced, fixed trip count) ----
    for (int i = tid; i < TT * UU; i += 256) {
        int t = i / UU, u = i - t * UU;
        bs[t * PAD + u] = bl[i];
    }
    for (int i = tid; i < TT * (UU - 1); i += 256) {
        int t = i / (UU - 1), u = i - t * (UU - 1);
        ls[t * PAD + u] = lb[i];
    }

    // ---- lengths (wave-redundant reduce) ----
    int acc = 0;
    for (int i = lane; i < TT; i += 64) acc += attn[b * TT + i];
    #pragma unroll
    for (int off = 32; off; off >>= 1) acc += __shfl_xor(acc, off);
    const int tmax = min(max(acc, 1), TT) - 1;
    int lab = lab_lens[b];
    lab = min(max(lab, 0), UU - 1);
    const int ndiag = tmax + lab + 1;

    __syncthreads();
    if (tid >= 64) return;          // recursion is wave 0 only; no barriers after

    const int uA = lane * 2;                 // even column
    const int uB = uA + 1;                   // odd column
    const int cA = min(uA, UU - 1);          // clamped LDS cols
    const int cB = min(uB, UU - 1);
    const int eA = min(max(uA - 1, 0), UU - 2);
    const int eB = min(uB - 1, UU - 2);

    auto fetch = [&](int d, float& fbA, float& flA, float& fbB, float& flB) {
        int tA = min(max(d - uA, 0), TT - 1);
        int tB = min(max(d - uB, 0), TT - 1);
        fbA = bs[tA * PAD + cA];
        flA = ls[tA * PAD + eA];
        fbB = bs[tB * PAD + cB];
        flB = ls[tB * PAD + eB];
    };

    float aA = -INFINITY, aB = -INFINITY;

    float cbA[4], clA[4], cbB[4], clB[4];
    float nbA[4], nlA[4], nbB[4], nlB[4];
    #pragma unroll
    for (int k = 0; k < 4; ++k) fetch(k, cbA[k], clA[k], cbB[k], clB[k]);

    const int ng = (ndiag + 3) >> 2;
    for (int g = 0; g < ng; ++g) {
        const int dbase = g * 4;
        #pragma unroll
        for (int k = 0; k < 4; ++k) fetch(dbase + 4 + k, nbA[k], nlA[k], nbB[k], nlB[k]);
        #pragma unroll
        for (int k = 0; k < 4; ++k) {
            const int d = dbase + k;
            if (d < ndiag) {                       // wave-uniform
                const float leftA = __shfl_up(aB, 1);   // alpha[d-1][uA-1] = lane l-1's B
                const float leftB = aA;                 // alpha[d-1][uB-1] in-register
                const int tA = d - uA;
                const int tB = d - uB;
                // slot A (even col)
                {
                    const float x  = aA + cbA[k];
                    const float y  = leftA + clA[k];
                    const float mx = fmaxf(x, y), mn = fminf(x, y);
                    const float full = mx + __logf(1.f + __expf(mn - mx));
                    const float v = (d == 0) ? cbA[k]
                                  : (uA == 0) ? x
                                  : (tA == 0) ? y
                                  : full;
                    const bool act = (uA <= lab) && (tA >= 0) && (tA <= tmax);
                    aA = act ? v : aA;
                }
                // slot B (odd col, uB >= 1; never active at d==0)
                {
                    const float x  = aB + cbB[k];
                    const float y  = leftB + clB[k];
                    const float mx = fmaxf(x, y), mn = fminf(x, y);
                    const float full = mx + __logf(1.f + __expf(mn - mx));
                    const float v = (tB == 0) ? y : full;
                    const bool act = (uB <= lab) && (tB >= 0) && (tB <= tmax);
                    aB = act ? v : aB;
                }
            }
        }
        #pragma unroll
        for (int k = 0; k < 4; ++k) { cbA[k] = nbA[k]; clA[k] = nlA[k];
                                      cbB[k] = nbB[k]; clB[k] = nlB[k]; }
    }

    // loss = -alpha[tmax, lab]; col lab -> lane lab>>1, slot (lab&1)
    const float cand = (lab & 1) ? aB : aA;
    const float v = __shfl(cand, lab >> 1);
    if (lane == 0) {
        loss_b[b]  = -v;
        valid_b[b] = (lab > 0) ? 1 : 0;
    }
}

// Kernel 3: mean over valid batch elements.
__global__ void finalize_kernel(const float* __restrict__ loss_b,
                                const int* __restrict__ valid_b,
                                float* __restrict__ out) {
    if (threadIdx.x == 0 && blockIdx.x == 0) {
        float s = 0.f;
        int nv = 0;
        for (int b = 0; b < BB; ++b) {
            if (valid_b[b]) { s += loss_b[b]; ++nv; }
        }
        out[0] = s / (float)max(nv, 1);
    }
}

extern "C" void kernel_launch(void* const* d_in, const int* in_sizes, int n_in,
                              void* d_out, int out_size, void* d_ws, size_t ws_size,
                              hipStream_t stream) {
    const float* logits   = (const float*)d_in[0];
    const int*   labels   = (const int*)d_in[1];
    const int*   lab_lens = (const int*)d_in[2];
    const int*   attn     = (const int*)d_in[3];

    float* ws      = (float*)d_ws;
    float* blank   = ws;                           // B*T*U
    float* label   = blank + BB * TT * UU;         // B*T*(U-1)
    float* loss_b  = label + BB * TT * (UU - 1);   // B
    int*   valid_b = (int*)(loss_b + BB);          // B

    static bool attr_set = false;
    if (!attr_set) {
        hipFuncSetAttribute((const void*)alpha_kernel,
                            hipFuncAttributeMaxDynamicSharedMemorySize,
                            2 * TT * PAD * (int)sizeof(float));   // 163,200 B <= 160 KiB
        attr_set = true;
    }

    lse_kernel<<<(NCELL + 3) / 4, 256, 0, stream>>>(logits, labels, lab_lens, blank, label);
    alpha_kernel<<<BB, 256, 2 * TT * PAD * sizeof(float), stream>>>(
        blank, label, lab_lens, attn, loss_b, valid_b);
    finalize_kernel<<<1, 64, 0, stream>>>(loss_b, valid_b, (float*)d_out);
}